// Round 4
// baseline (942.667 us; speedup 1.0000x reference)
//
#include <hip/hip_runtime.h>

#define T_SEQ 256

typedef __bf16 bf16x8 __attribute__((ext_vector_type(8)));
typedef float f32x4 __attribute__((ext_vector_type(4)));
typedef unsigned short u16x8 __attribute__((ext_vector_type(8)));

// LDS geometry
#define XPT 136            // per-t stride (272 B, 16B aligned, 8-bank skew)
#define XPI 4360           // per-batch-row stride (32*136 bf16 or 2*16*136 fp32 hi/lo)
#define PH  72             // h row stride
#define HSZ 1152           // one h buffer: 16 rows * PH

__device__ __forceinline__ float b2f(unsigned short u) {
    union { unsigned int i; float f; } v; v.i = ((unsigned int)u) << 16; return v.f;
}
__device__ __forceinline__ unsigned short f2b(float f) {
    unsigned int x = __builtin_bit_cast(unsigned int, f);
    unsigned int r = (x + 0x7fffu + ((x >> 16) & 1u)) >> 16;
    return (unsigned short)r;
}
__device__ __forceinline__ float sigmoid_f(float x) {
    float e = __builtin_amdgcn_exp2f(-1.4426950408889634f * x);
    return __builtin_amdgcn_rcpf(1.0f + e);
}
__device__ __forceinline__ float tanh_f(float x) {
    float e = __builtin_amdgcn_exp2f(-2.8853900817779268f * x);
    return 2.0f * __builtin_amdgcn_rcpf(1.0f + e) - 1.0f;
}

// ---------------- prep: dtype probe only. ws = 4-byte flag.
// bf16 data -> bits 14:7 of each dword are a sane bf16 exponent ~always;
// fp32 data -> those are mantissa bits, sane ~12% of the time.
__global__ __launch_bounds__(256) void prep_kernel(const void* w_fc, int* ws_flag)
{
    __shared__ int scount;
    const int tid = threadIdx.x;
    if (tid == 0) scount = 0;
    __syncthreads();
    const unsigned int* dw = (const unsigned int*)w_fc;
    int cnt = 0;
    for (int i = tid; i < 4096; i += 256) {       // 4096 dwords valid for either dtype
        const unsigned int e = (dw[i] >> 7) & 0xFFu;
        if (e >= 0x60u && e <= 0x7Fu) ++cnt;
    }
    atomicAdd(&scount, cnt);
    __syncthreads();
    if (tid == 0) *ws_flag = (scount > 2048) ? 1 : 0;
}

// load one B-fragment (8 weights along k, row n of row-major [4H][K]) as hi(/lo)
template <int IS_BF16>
__device__ __forceinline__ void load_frag(const void* wp, int n, int K, int k0,
                                          bf16x8& hi, bf16x8& lo) {
    if (IS_BF16) {
        hi = *(const bf16x8*)((const unsigned short*)wp + (size_t)n * K + k0);
    } else {
        const float* wf = (const float*)wp + (size_t)n * K + k0;
        #pragma unroll
        for (int j = 0; j < 8; ++j) {
            const float v = wf[j];
            const unsigned short h = f2b(v);
            hi[j] = __builtin_bit_cast(__bf16, h);
            lo[j] = __builtin_bit_cast(__bf16, f2b(v - b2f(h)));
        }
    }
}

// ---------------- mega: fused 2-layer LSTM + head. 64 blocks x 16 batch rows.
// fp32-faithful: weights/x/h all carried as hi+lo bf16 planes through MFMA
// (fp32 path computes Ah*Wh + Ah*Wl + Al*Wh per GEMM; bf16 path is exact).
// Wave w owns hidden units u=w*16+l16; each lane holds i,f,g,o of its own
// cells (gate n-tiles g*4+w) -> lane-local gate math, no shuffles.
template <int IS_BF16>
__global__ __launch_bounds__(256, 1) void mega_kernel(
    const void* x,
    const void* wih0p, const void* whh0p, const void* bih0p, const void* bhh0p,
    const void* wih1p, const void* whh1p, const void* bih1p, const void* bhh1p,
    const void* wfcp, const void* bfcp,
    const int* ws_flag, void* out)
{
    extern __shared__ __align__(16) unsigned short smem[];
    const int flag = *ws_flag;
    if (flag != IS_BF16) return;           // wrong-dtype instantiation: no-op

    unsigned short* xs  = smem;            // [16][XPI]
    unsigned short* h0h = smem + 16 * XPI; // [2][HSZ] h0 hi (parity)
    unsigned short* h0o = h0h + 2 * HSZ;   // [2][HSZ] h0 lo
    unsigned short* h1h = h0h + 4 * HSZ;   // [2][HSZ] h1 hi
    unsigned short* h1o = h0h + 6 * HSZ;   // [2][HSZ] h1 lo

    const int tid = threadIdx.x;
    const int lane = tid & 63, w = tid >> 6;
    const int l16 = lane & 15, quad = lane >> 4;
    const int b0 = blockIdx.x * 16;
    const int k0 = quad * 8;

    // ---- weight fragments resident in registers, built from original inputs
    bf16x8 fih0h[4][4], fhh0h[4][2], fih1h[4][2], fhh1h[4][2];
    bf16x8 fih0l[4][4], fhh0l[4][2], fih1l[4][2], fhh1l[4][2];  // fp32 path only
    float gb0r[4], gb1r[4];
    #pragma unroll
    for (int g = 0; g < 4; ++g) {
        const int n = g * 64 + w * 16 + l16;   // == (g*4+w)*16 + l16
        #pragma unroll
        for (int ks = 0; ks < 4; ++ks)
            load_frag<IS_BF16>(wih0p, n, 128, ks * 32 + k0, fih0h[g][ks], fih0l[g][ks]);
        #pragma unroll
        for (int ks = 0; ks < 2; ++ks) {
            load_frag<IS_BF16>(whh0p, n, 64, ks * 32 + k0, fhh0h[g][ks], fhh0l[g][ks]);
            load_frag<IS_BF16>(wih1p, n, 64, ks * 32 + k0, fih1h[g][ks], fih1l[g][ks]);
            load_frag<IS_BF16>(whh1p, n, 64, ks * 32 + k0, fhh1h[g][ks], fhh1l[g][ks]);
        }
        if (IS_BF16) {
            gb0r[g] = b2f(((const unsigned short*)bih0p)[n]) + b2f(((const unsigned short*)bhh0p)[n]);
            gb1r[g] = b2f(((const unsigned short*)bih1p)[n]) + b2f(((const unsigned short*)bhh1p)[n]);
        } else {
            gb0r[g] = ((const float*)bih0p)[n] + ((const float*)bhh0p)[n];
            gb1r[g] = ((const float*)bih1p)[n] + ((const float*)bhh1p)[n];
        }
    }

    for (int i = tid; i < 8 * HSZ; i += 256) h0h[i] = 0;   // zero all h planes

    float c0[4] = {0.f, 0.f, 0.f, 0.f}, c1[4] = {0.f, 0.f, 0.f, 0.f};

    const int CS  = IS_BF16 ? 32 : 16;     // timesteps staged per LDS chunk
    const int NCH = T_SEQ / CS;

    for (int tc = 0; tc < NCH; ++tc) {
        __syncthreads();                   // prior chunk's xs reads complete
        if (IS_BF16) {
            // x bf16 [B][128][256]: stage 16 rows x 128 d x 32 t (exact)
            for (int l = 0; l < 32; ++l) {
                const int e = l * 256 + tid;         // e = i*512 + d*4 + c
                const int c = e & 3, d = (e >> 2) & 127, i = e >> 9;
                const u16x8 v = *(const u16x8*)((const unsigned short*)x +
                    (((size_t)(b0 + i) * 128 + d) * 256 + tc * 32 + c * 8));
                #pragma unroll
                for (int j = 0; j < 8; ++j)
                    xs[i * XPI + (c * 8 + j) * XPT + d] = v[j];
            }
        } else {
            // x fp32 [B][128][256]: stage 16 rows x 128 d x 16 t as hi/lo planes
            for (int l = 0; l < 32; ++l) {
                const int e = l * 256 + tid;         // e = i*512 + d*4 + c
                const int c = e & 3, d = (e >> 2) & 127, i = e >> 9;
                const float4 v = *(const float4*)((const float*)x +
                    (((size_t)(b0 + i) * 128 + d) * 256 + tc * 16 + c * 4));
                const float vv[4] = {v.x, v.y, v.z, v.w};
                #pragma unroll
                for (int j = 0; j < 4; ++j) {
                    const unsigned short hi = f2b(vv[j]);
                    xs[i * XPI + (c * 4 + j) * XPT + d] = hi;
                    xs[i * XPI + 2176 + (c * 4 + j) * XPT + d] = f2b(vv[j] - b2f(hi));
                }
            }
        }
        __syncthreads();

        for (int tt = 0; tt < CS; ++tt) {
            const int t = tc * CS + tt;
            const int p = t & 1, q = p ^ 1;

            // ---- layer 0: gates = x_t@W_ih0^T + h0@W_hh0^T + bias
            bf16x8 xa[4], xo[4], hh[2], ho[2];
            #pragma unroll
            for (int ks = 0; ks < 4; ++ks)
                xa[ks] = *(const bf16x8*)(&xs[l16 * XPI + tt * XPT + ks * 32 + k0]);
            if (!IS_BF16)
                #pragma unroll
                for (int ks = 0; ks < 4; ++ks)
                    xo[ks] = *(const bf16x8*)(&xs[l16 * XPI + 2176 + tt * XPT + ks * 32 + k0]);
            #pragma unroll
            for (int ks = 0; ks < 2; ++ks) {
                hh[ks] = *(const bf16x8*)(&h0h[p * HSZ + l16 * PH + ks * 32 + k0]);
                ho[ks] = *(const bf16x8*)(&h0o[p * HSZ + l16 * PH + ks * 32 + k0]);
            }
            f32x4 acc[4];
            #pragma unroll
            for (int g = 0; g < 4; ++g)
                acc[g] = (f32x4){gb0r[g], gb0r[g], gb0r[g], gb0r[g]};
            #pragma unroll
            for (int g = 0; g < 4; ++g) {
                #pragma unroll
                for (int ks = 0; ks < 4; ++ks) {
                    acc[g] = __builtin_amdgcn_mfma_f32_16x16x32_bf16(xa[ks], fih0h[g][ks], acc[g], 0, 0, 0);
                    if (!IS_BF16) {
                        acc[g] = __builtin_amdgcn_mfma_f32_16x16x32_bf16(xa[ks], fih0l[g][ks], acc[g], 0, 0, 0);
                        acc[g] = __builtin_amdgcn_mfma_f32_16x16x32_bf16(xo[ks], fih0h[g][ks], acc[g], 0, 0, 0);
                    }
                }
                #pragma unroll
                for (int ks = 0; ks < 2; ++ks) {
                    acc[g] = __builtin_amdgcn_mfma_f32_16x16x32_bf16(hh[ks], fhh0h[g][ks], acc[g], 0, 0, 0);
                    acc[g] = __builtin_amdgcn_mfma_f32_16x16x32_bf16(ho[ks], fhh0h[g][ks], acc[g], 0, 0, 0);
                    if (!IS_BF16)
                        acc[g] = __builtin_amdgcn_mfma_f32_16x16x32_bf16(hh[ks], fhh0l[g][ks], acc[g], 0, 0, 0);
                }
            }
            #pragma unroll
            for (int r = 0; r < 4; ++r) {
                const float gi = sigmoid_f(acc[0][r]);
                const float gf = sigmoid_f(acc[1][r]);
                const float gg = tanh_f(acc[2][r]);
                const float go = sigmoid_f(acc[3][r]);
                c0[r] = gf * c0[r] + gi * gg;
                const float hv = go * tanh_f(c0[r]);
                const unsigned short hb = f2b(hv);
                const int idx = q * HSZ + (quad * 4 + r) * PH + w * 16 + l16;
                h0h[idx] = hb;
                h0o[idx] = f2b(hv - b2f(hb));
            }
            __syncthreads();   // h0(new) visible

            // ---- layer 1: gates = h0_new@W_ih1^T + h1@W_hh1^T + bias
            bf16x8 ah[2], ao[2], bh[2], bo[2];
            #pragma unroll
            for (int ks = 0; ks < 2; ++ks) {
                ah[ks] = *(const bf16x8*)(&h0h[q * HSZ + l16 * PH + ks * 32 + k0]);
                ao[ks] = *(const bf16x8*)(&h0o[q * HSZ + l16 * PH + ks * 32 + k0]);
                bh[ks] = *(const bf16x8*)(&h1h[p * HSZ + l16 * PH + ks * 32 + k0]);
                bo[ks] = *(const bf16x8*)(&h1o[p * HSZ + l16 * PH + ks * 32 + k0]);
            }
            #pragma unroll
            for (int g = 0; g < 4; ++g)
                acc[g] = (f32x4){gb1r[g], gb1r[g], gb1r[g], gb1r[g]};
            #pragma unroll
            for (int g = 0; g < 4; ++g) {
                #pragma unroll
                for (int ks = 0; ks < 2; ++ks) {
                    acc[g] = __builtin_amdgcn_mfma_f32_16x16x32_bf16(ah[ks], fih1h[g][ks], acc[g], 0, 0, 0);
                    acc[g] = __builtin_amdgcn_mfma_f32_16x16x32_bf16(ao[ks], fih1h[g][ks], acc[g], 0, 0, 0);
                    acc[g] = __builtin_amdgcn_mfma_f32_16x16x32_bf16(bh[ks], fhh1h[g][ks], acc[g], 0, 0, 0);
                    acc[g] = __builtin_amdgcn_mfma_f32_16x16x32_bf16(bo[ks], fhh1h[g][ks], acc[g], 0, 0, 0);
                    if (!IS_BF16) {
                        acc[g] = __builtin_amdgcn_mfma_f32_16x16x32_bf16(ah[ks], fih1l[g][ks], acc[g], 0, 0, 0);
                        acc[g] = __builtin_amdgcn_mfma_f32_16x16x32_bf16(bh[ks], fhh1l[g][ks], acc[g], 0, 0, 0);
                    }
                }
            }
            #pragma unroll
            for (int r = 0; r < 4; ++r) {
                const float gi = sigmoid_f(acc[0][r]);
                const float gf = sigmoid_f(acc[1][r]);
                const float gg = tanh_f(acc[2][r]);
                const float go = sigmoid_f(acc[3][r]);
                c1[r] = gf * c1[r] + gi * gg;
                const float hv = go * tanh_f(c1[r]);
                const unsigned short hb = f2b(hv);
                const int idx = q * HSZ + (quad * 4 + r) * PH + w * 16 + l16;
                h1h[idx] = hb;
                h1o[idx] = f2b(hv - b2f(hb));
            }
            __syncthreads();
        }
    }

    // ---- head: scores[m][n] = sum_k h1_final[m][k]*w_fc[n][k] + b_fc[n]
    // t=255 wrote parity q=0.
    const int n  = tid & 127;
    const int mb = (tid >> 7) * 8;
    float s[8] = {0.f, 0.f, 0.f, 0.f, 0.f, 0.f, 0.f, 0.f};
    for (int k = 0; k < 64; ++k) {
        const float wv = IS_BF16 ? b2f(((const unsigned short*)wfcp)[n * 64 + k])
                                 : ((const float*)wfcp)[n * 64 + k];
        #pragma unroll
        for (int m = 0; m < 8; ++m) {
            const int idx = (mb + m) * PH + k;
            s[m] += (b2f(h1h[idx]) + b2f(h1o[idx])) * wv;
        }
    }
    const float bias = IS_BF16 ? b2f(((const unsigned short*)bfcp)[n])
                               : ((const float*)bfcp)[n];
    if (IS_BF16) {
        unsigned short* o16 = (unsigned short*)out;
        #pragma unroll
        for (int m = 0; m < 8; ++m)
            o16[(size_t)(b0 + mb + m) * 128 + n] = f2b(s[m] + bias);
    } else {
        float* of = (float*)out;
        #pragma unroll
        for (int m = 0; m < 8; ++m)
            of[(size_t)(b0 + mb + m) * 128 + n] = s[m] + bias;
    }
}

extern "C" void kernel_launch(void* const* d_in, const int* in_sizes, int n_in,
                              void* d_out, int out_size, void* d_ws, size_t ws_size,
                              hipStream_t stream) {
    int* ws_flag = (int*)d_ws;   // only 4 bytes of workspace used

    prep_kernel<<<1, 256, 0, stream>>>(d_in[9], ws_flag);

    const size_t lds_bytes = (16 * XPI + 8 * HSZ) * sizeof(unsigned short); // 157,952
    mega_kernel<1><<<64, 256, lds_bytes, stream>>>(
        d_in[0], d_in[1], d_in[2], d_in[3], d_in[4],
        d_in[5], d_in[6], d_in[7], d_in[8], d_in[9], d_in[10], ws_flag, d_out);
    mega_kernel<0><<<64, 256, lds_bytes, stream>>>(
        d_in[0], d_in[1], d_in[2], d_in[3], d_in[4],
        d_in[5], d_in[6], d_in[7], d_in[8], d_in[9], d_in[10], ws_flag, d_out);
}

// Round 5
// 686.353 us; speedup vs baseline: 1.3734x; 1.3734x over previous
//
#include <hip/hip_runtime.h>

#define T_SEQ 256
#define PH  72
#define HSZ 1152

typedef __bf16 bf16x8 __attribute__((ext_vector_type(8)));
typedef float f32x4 __attribute__((ext_vector_type(4)));

__device__ __forceinline__ float b2f(unsigned short u) {
    union { unsigned int i; float f; } v; v.i = ((unsigned int)u) << 16; return v.f;
}
__device__ __forceinline__ unsigned short f2b(float f) {
    unsigned int x = __builtin_bit_cast(unsigned int, f);
    unsigned int r = (x + 0x7fffu + ((x >> 16) & 1u)) >> 16;
    return (unsigned short)r;
}
__device__ __forceinline__ float sigmoid_f(float x) {
    float e = __builtin_amdgcn_exp2f(-1.4426950408889634f * x);
    return __builtin_amdgcn_rcpf(1.0f + e);
}
__device__ __forceinline__ float tanh_f(float x) {
    float e = __builtin_amdgcn_exp2f(-2.8853900817779268f * x);
    return 2.0f * __builtin_amdgcn_rcpf(1.0f + e) - 1.0f;
}
// fp32 weight row -> hi/lo bf16 fragments (8 along k)
__device__ __forceinline__ void load_frag32(const float* wp, int n, int K, int k0,
                                            bf16x8& hi, bf16x8& lo) {
    const float* wf = wp + (size_t)n * K + k0;
    #pragma unroll
    for (int j = 0; j < 8; ++j) {
        const float v = wf[j];
        const unsigned short h = f2b(v);
        hi[j] = __builtin_bit_cast(__bf16, h);
        lo[j] = __builtin_bit_cast(__bf16, f2b(v - b2f(h)));
    }
}

#define MFMA(a, b, c) __builtin_amdgcn_mfma_f32_16x16x32_bf16(a, b, c, 0, 0, 0)

// ================= proj0: xp[bb][t][g][m][n2] (fp16, bias folded) =================
// xp flat idx = (((bb*256+t)*4+g)*16 + m)*64 + n2 ; m=batch row in block, n2=w*16+l16
#define XT   136    // per-t LDS stride (elems)
#define XROW 1096   // per-row LDS stride (8*136 + 8 pad -> bank offset 4/row)
__global__ __launch_bounds__(256) void proj0_kernel(
    const float* __restrict__ x, const float* __restrict__ wih0,
    const float* __restrict__ bih0, const float* __restrict__ bhh0,
    _Float16* __restrict__ xp)
{
    __shared__ unsigned short xh[16 * XROW];
    __shared__ unsigned short xl[16 * XROW];
    const int bb = blockIdx.x >> 2;
    const int tt = (blockIdx.x & 3) * 64;
    const int tid = threadIdx.x, lane = tid & 63, w = tid >> 6;
    const int l16 = lane & 15, quad = lane >> 4, k0 = quad * 8;

    bf16x8 fwh[4][4], fwl[4][4];
    float gb[4];
    #pragma unroll
    for (int g = 0; g < 4; ++g) {
        const int n = g * 64 + w * 16 + l16;
        #pragma unroll
        for (int ks = 0; ks < 4; ++ks)
            load_frag32(wih0, n, 128, ks * 32 + k0, fwh[g][ks], fwl[g][ks]);
        gb[g] = bih0[n] + bhh0[n];
    }

    for (int win = 0; win < 8; ++win) {          // 8 timesteps per window
        __syncthreads();
        #pragma unroll
        for (int it = 0; it < 16; ++it) {        // stage 16 rows x 128 d x 8 t, hi/lo
            const int e = it * 256 + tid;        // e = row*256 + d*2 + t4
            const int t4 = e & 1, d = (e >> 1) & 127, row = e >> 8;
            const float4 v = *(const float4*)(x +
                ((size_t)(bb * 16 + row) * 128 + d) * 256 + tt + win * 8 + t4 * 4);
            const float vv[4] = {v.x, v.y, v.z, v.w};
            #pragma unroll
            for (int j = 0; j < 4; ++j) {
                const unsigned short hb = f2b(vv[j]);
                const int a = row * XROW + (t4 * 4 + j) * XT + d;
                xh[a] = hb;
                xl[a] = f2b(vv[j] - b2f(hb));
            }
        }
        __syncthreads();
        for (int tl = 0; tl < 8; ++tl) {
            const int t = tt + win * 8 + tl;
            bf16x8 a_h[4], a_l[4];
            #pragma unroll
            for (int ks = 0; ks < 4; ++ks) {
                a_h[ks] = *(const bf16x8*)&xh[l16 * XROW + tl * XT + ks * 32 + k0];
                a_l[ks] = *(const bf16x8*)&xl[l16 * XROW + tl * XT + ks * 32 + k0];
            }
            f32x4 acc[4];
            #pragma unroll
            for (int g = 0; g < 4; ++g)
                acc[g] = (f32x4){gb[g], gb[g], gb[g], gb[g]};
            #pragma unroll
            for (int g = 0; g < 4; ++g)
                #pragma unroll
                for (int ks = 0; ks < 4; ++ks) {
                    acc[g] = MFMA(a_h[ks], fwh[g][ks], acc[g]);
                    acc[g] = MFMA(a_h[ks], fwl[g][ks], acc[g]);
                    acc[g] = MFMA(a_l[ks], fwh[g][ks], acc[g]);
                }
            #pragma unroll
            for (int g = 0; g < 4; ++g)
                #pragma unroll
                for (int r = 0; r < 4; ++r)
                    xp[(((size_t)(bb * 256 + t) * 4 + g) * 16 + quad * 4 + r) * 64
                       + w * 16 + l16] = (_Float16)acc[g][r];
        }
    }
}

// ================= rec: 2-layer recurrence, 1 barrier/step, 72 MFMA/step =================
// Phase t: layer1[t] (needs h0[t] slot t&1, h1[t-1] slot (t&1)^1) + layer0[t+1]
// (needs h0[t], xp[t+1] prefetched). Writes h1[t]->slot t&1, h0[t+1]->slot (t&1)^1.
// No same-phase slot overlap between reads and writes -> single barrier race-free.
__global__ __launch_bounds__(256, 1) void rec_kernel(
    const _Float16* __restrict__ xp,
    const float* __restrict__ whh0, const float* __restrict__ wih1,
    const float* __restrict__ whh1, const float* __restrict__ bih1,
    const float* __restrict__ bhh1, const float* __restrict__ wfc,
    const float* __restrict__ bfc, float* __restrict__ out)
{
    __shared__ unsigned short h0h[2 * HSZ], h0o[2 * HSZ], h1h[2 * HSZ], h1o[2 * HSZ];
    const int tid = threadIdx.x, lane = tid & 63, w = tid >> 6;
    const int l16 = lane & 15, quad = lane >> 4, k0 = quad * 8;
    const int bb = blockIdx.x;

    bf16x8 f00h[4][2], f00l[4][2], f10h[4][2], f10l[4][2], f11h[4][2], f11l[4][2];
    float gb1[4];
    #pragma unroll
    for (int g = 0; g < 4; ++g) {
        const int n = g * 64 + w * 16 + l16;
        #pragma unroll
        for (int ks = 0; ks < 2; ++ks) {
            load_frag32(whh0, n, 64, ks * 32 + k0, f00h[g][ks], f00l[g][ks]);
            load_frag32(wih1, n, 64, ks * 32 + k0, f10h[g][ks], f10l[g][ks]);
            load_frag32(whh1, n, 64, ks * 32 + k0, f11h[g][ks], f11l[g][ks]);
        }
        gb1[g] = bih1[n] + bhh1[n];
    }
    for (int i = tid; i < 2 * HSZ; i += 256) {
        h0h[i] = 0; h0o[i] = 0; h1h[i] = 0; h1o[i] = 0;
    }

    float c0[4] = {0.f, 0.f, 0.f, 0.f}, c1[4] = {0.f, 0.f, 0.f, 0.f};

    const size_t lb = (size_t)quad * 4 * 64 + w * 16 + l16;  // + r*64 + g*1024 + (bb*256+t)*4096
    const size_t base0 = (size_t)bb * 256 * 4096;

    _Float16 xc[16], xn[16];
    #pragma unroll
    for (int g = 0; g < 4; ++g)
        #pragma unroll
        for (int r = 0; r < 4; ++r) {
            xc[g * 4 + r] = xp[base0 + (size_t)g * 1024 + r * 64 + lb];          // t=0
            xn[g * 4 + r] = xp[base0 + 4096 + (size_t)g * 1024 + r * 64 + lb];   // t=1
        }
    // layer0[0]: gates = xp[0] (h0_init = 0) -> h0[0] slot 0
    #pragma unroll
    for (int r = 0; r < 4; ++r) {
        const float gi = sigmoid_f((float)xc[r]);
        const float gf = sigmoid_f((float)xc[4 + r]); (void)gf;  // f*c0(=0)
        const float gg = tanh_f((float)xc[8 + r]);
        const float go = sigmoid_f((float)xc[12 + r]);
        c0[r] = gi * gg;
        const float hv = go * tanh_f(c0[r]);
        const unsigned short hb = f2b(hv);
        const int idx = (quad * 4 + r) * PH + w * 16 + l16;
        h0h[idx] = hb; h0o[idx] = f2b(hv - b2f(hb));
    }
    __syncthreads();

    for (int t = 0; t < 255; ++t) {
        const int s0 = t & 1, s1 = s0 ^ 1;
        #pragma unroll
        for (int i = 0; i < 16; ++i) xc[i] = xn[i];
        const int tp = (t + 2 < 256) ? t + 2 : 255;
        const size_t bt = base0 + (size_t)tp * 4096;
        #pragma unroll
        for (int g = 0; g < 4; ++g)
            #pragma unroll
            for (int r = 0; r < 4; ++r)
                xn[g * 4 + r] = xp[bt + (size_t)g * 1024 + r * 64 + lb];

        bf16x8 ah[2], ao[2], bh[2], bo[2];
        #pragma unroll
        for (int ks = 0; ks < 2; ++ks) {
            ah[ks] = *(const bf16x8*)&h0h[s0 * HSZ + l16 * PH + ks * 32 + k0];
            ao[ks] = *(const bf16x8*)&h0o[s0 * HSZ + l16 * PH + ks * 32 + k0];
            bh[ks] = *(const bf16x8*)&h1h[s1 * HSZ + l16 * PH + ks * 32 + k0];
            bo[ks] = *(const bf16x8*)&h1o[s1 * HSZ + l16 * PH + ks * 32 + k0];
        }
        f32x4 a1[4], a0[4];
        #pragma unroll
        for (int g = 0; g < 4; ++g) {
            a1[g] = (f32x4){gb1[g], gb1[g], gb1[g], gb1[g]};
            a0[g] = (f32x4){(float)xc[g * 4 + 0], (float)xc[g * 4 + 1],
                            (float)xc[g * 4 + 2], (float)xc[g * 4 + 3]};
        }
        #pragma unroll
        for (int g = 0; g < 4; ++g)
            #pragma unroll
            for (int ks = 0; ks < 2; ++ks) {
                a1[g] = MFMA(ah[ks], f10h[g][ks], a1[g]);
                a1[g] = MFMA(ah[ks], f10l[g][ks], a1[g]);
                a1[g] = MFMA(ao[ks], f10h[g][ks], a1[g]);
                a1[g] = MFMA(bh[ks], f11h[g][ks], a1[g]);
                a1[g] = MFMA(bh[ks], f11l[g][ks], a1[g]);
                a1[g] = MFMA(bo[ks], f11h[g][ks], a1[g]);
                a0[g] = MFMA(ah[ks], f00h[g][ks], a0[g]);
                a0[g] = MFMA(ah[ks], f00l[g][ks], a0[g]);
                a0[g] = MFMA(ao[ks], f00h[g][ks], a0[g]);
            }
        #pragma unroll
        for (int r = 0; r < 4; ++r) {
            {   // layer1[t] -> h1 slot s0
                const float gi = sigmoid_f(a1[0][r]);
                const float gf = sigmoid_f(a1[1][r]);
                const float gg = tanh_f(a1[2][r]);
                const float go = sigmoid_f(a1[3][r]);
                c1[r] = gf * c1[r] + gi * gg;
                const float hv = go * tanh_f(c1[r]);
                const unsigned short hb = f2b(hv);
                const int idx = s0 * HSZ + (quad * 4 + r) * PH + w * 16 + l16;
                h1h[idx] = hb; h1o[idx] = f2b(hv - b2f(hb));
            }
            {   // layer0[t+1] -> h0 slot s1
                const float gi = sigmoid_f(a0[0][r]);
                const float gf = sigmoid_f(a0[1][r]);
                const float gg = tanh_f(a0[2][r]);
                const float go = sigmoid_f(a0[3][r]);
                c0[r] = gf * c0[r] + gi * gg;
                const float hv = go * tanh_f(c0[r]);
                const unsigned short hb = f2b(hv);
                const int idx = s1 * HSZ + (quad * 4 + r) * PH + w * 16 + l16;
                h0h[idx] = hb; h0o[idx] = f2b(hv - b2f(hb));
            }
        }
        __syncthreads();
    }

    // epilogue: layer1[255]  (h0[255] slot 1, h1[254] slot 0) -> h1[255] slot 1
    {
        bf16x8 ah[2], ao[2], bh[2], bo[2];
        #pragma unroll
        for (int ks = 0; ks < 2; ++ks) {
            ah[ks] = *(const bf16x8*)&h0h[HSZ + l16 * PH + ks * 32 + k0];
            ao[ks] = *(const bf16x8*)&h0o[HSZ + l16 * PH + ks * 32 + k0];
            bh[ks] = *(const bf16x8*)&h1h[l16 * PH + ks * 32 + k0];
            bo[ks] = *(const bf16x8*)&h1o[l16 * PH + ks * 32 + k0];
        }
        f32x4 a1[4];
        #pragma unroll
        for (int g = 0; g < 4; ++g)
            a1[g] = (f32x4){gb1[g], gb1[g], gb1[g], gb1[g]};
        #pragma unroll
        for (int g = 0; g < 4; ++g)
            #pragma unroll
            for (int ks = 0; ks < 2; ++ks) {
                a1[g] = MFMA(ah[ks], f10h[g][ks], a1[g]);
                a1[g] = MFMA(ah[ks], f10l[g][ks], a1[g]);
                a1[g] = MFMA(ao[ks], f10h[g][ks], a1[g]);
                a1[g] = MFMA(bh[ks], f11h[g][ks], a1[g]);
                a1[g] = MFMA(bh[ks], f11l[g][ks], a1[g]);
                a1[g] = MFMA(bo[ks], f11h[g][ks], a1[g]);
            }
        #pragma unroll
        for (int r = 0; r < 4; ++r) {
            const float gi = sigmoid_f(a1[0][r]);
            const float gf = sigmoid_f(a1[1][r]);
            const float gg = tanh_f(a1[2][r]);
            const float go = sigmoid_f(a1[3][r]);
            c1[r] = gf * c1[r] + gi * gg;
            const float hv = go * tanh_f(c1[r]);
            const unsigned short hb = f2b(hv);
            const int idx = HSZ + (quad * 4 + r) * PH + w * 16 + l16;
            h1h[idx] = hb; h1o[idx] = f2b(hv - b2f(hb));
        }
    }
    __syncthreads();

    // head: scores[m][n] = sum_k h1[m][k]*wfc[n][k] + bfc[n]   (h1 final: slot 1)
    const int n  = tid & 127;
    const int mb = (tid >> 7) * 8;
    float s[8] = {0.f, 0.f, 0.f, 0.f, 0.f, 0.f, 0.f, 0.f};
    for (int k = 0; k < 64; ++k) {
        const float wv = wfc[n * 64 + k];
        #pragma unroll
        for (int m = 0; m < 8; ++m) {
            const int idx = HSZ + (mb + m) * PH + k;
            s[m] += (b2f(h1h[idx]) + b2f(h1o[idx])) * wv;
        }
    }
    #pragma unroll
    for (int m = 0; m < 8; ++m)
        out[(size_t)(bb * 16 + mb + m) * 128 + n] = s[m] + bfc[n];
}

// ================= fallback: R4's proven fused kernel (fp32 path) =================
#define XPT 136
#define XPI 4360
__global__ __launch_bounds__(256, 1) void mega_fb(
    const float* __restrict__ x,
    const float* wih0p, const float* whh0p, const float* bih0p, const float* bhh0p,
    const float* wih1p, const float* whh1p, const float* bih1p, const float* bhh1p,
    const float* wfcp, const float* bfcp, float* out)
{
    extern __shared__ __align__(16) unsigned short smem[];
    unsigned short* xs  = smem;
    unsigned short* h0h = smem + 16 * XPI;
    unsigned short* h0o = h0h + 2 * HSZ;
    unsigned short* h1h = h0h + 4 * HSZ;
    unsigned short* h1o = h0h + 6 * HSZ;

    const int tid = threadIdx.x, lane = tid & 63, w = tid >> 6;
    const int l16 = lane & 15, quad = lane >> 4;
    const int b0 = blockIdx.x * 16, k0 = quad * 8;

    bf16x8 fih0h[4][4], fih0l[4][4], fhh0h[4][2], fhh0l[4][2];
    bf16x8 fih1h[4][2], fih1l[4][2], fhh1h[4][2], fhh1l[4][2];
    float gb0r[4], gb1r[4];
    #pragma unroll
    for (int g = 0; g < 4; ++g) {
        const int n = g * 64 + w * 16 + l16;
        #pragma unroll
        for (int ks = 0; ks < 4; ++ks)
            load_frag32(wih0p, n, 128, ks * 32 + k0, fih0h[g][ks], fih0l[g][ks]);
        #pragma unroll
        for (int ks = 0; ks < 2; ++ks) {
            load_frag32(whh0p, n, 64, ks * 32 + k0, fhh0h[g][ks], fhh0l[g][ks]);
            load_frag32(wih1p, n, 64, ks * 32 + k0, fih1h[g][ks], fih1l[g][ks]);
            load_frag32(whh1p, n, 64, ks * 32 + k0, fhh1h[g][ks], fhh1l[g][ks]);
        }
        gb0r[g] = bih0p[n] + bhh0p[n];
        gb1r[g] = bih1p[n] + bhh1p[n];
    }
    for (int i = tid; i < 8 * HSZ; i += 256) h0h[i] = 0;
    float c0[4] = {0.f, 0.f, 0.f, 0.f}, c1[4] = {0.f, 0.f, 0.f, 0.f};

    for (int tc = 0; tc < 16; ++tc) {
        __syncthreads();
        for (int l = 0; l < 32; ++l) {
            const int e = l * 256 + tid;
            const int c = e & 3, d = (e >> 2) & 127, i = e >> 9;
            const float4 v = *(const float4*)(x +
                (((size_t)(b0 + i) * 128 + d) * 256 + tc * 16 + c * 4));
            const float vv[4] = {v.x, v.y, v.z, v.w};
            #pragma unroll
            for (int j = 0; j < 4; ++j) {
                const unsigned short hi = f2b(vv[j]);
                xs[i * XPI + (c * 4 + j) * XPT + d] = hi;
                xs[i * XPI + 2176 + (c * 4 + j) * XPT + d] = f2b(vv[j] - b2f(hi));
            }
        }
        __syncthreads();
        for (int tt = 0; tt < 16; ++tt) {
            const int t = tc * 16 + tt;
            const int p = t & 1, q = p ^ 1;
            bf16x8 xa[4], xo[4], hh[2], ho[2];
            #pragma unroll
            for (int ks = 0; ks < 4; ++ks) {
                xa[ks] = *(const bf16x8*)&xs[l16 * XPI + tt * XPT + ks * 32 + k0];
                xo[ks] = *(const bf16x8*)&xs[l16 * XPI + 2176 + tt * XPT + ks * 32 + k0];
            }
            #pragma unroll
            for (int ks = 0; ks < 2; ++ks) {
                hh[ks] = *(const bf16x8*)&h0h[p * HSZ + l16 * PH + ks * 32 + k0];
                ho[ks] = *(const bf16x8*)&h0o[p * HSZ + l16 * PH + ks * 32 + k0];
            }
            f32x4 acc[4];
            #pragma unroll
            for (int g = 0; g < 4; ++g)
                acc[g] = (f32x4){gb0r[g], gb0r[g], gb0r[g], gb0r[g]};
            #pragma unroll
            for (int g = 0; g < 4; ++g) {
                #pragma unroll
                for (int ks = 0; ks < 4; ++ks) {
                    acc[g] = MFMA(xa[ks], fih0h[g][ks], acc[g]);
                    acc[g] = MFMA(xa[ks], fih0l[g][ks], acc[g]);
                    acc[g] = MFMA(xo[ks], fih0h[g][ks], acc[g]);
                }
                #pragma unroll
                for (int ks = 0; ks < 2; ++ks) {
                    acc[g] = MFMA(hh[ks], fhh0h[g][ks], acc[g]);
                    acc[g] = MFMA(ho[ks], fhh0h[g][ks], acc[g]);
                    acc[g] = MFMA(hh[ks], fhh0l[g][ks], acc[g]);
                }
            }
            #pragma unroll
            for (int r = 0; r < 4; ++r) {
                const float gi = sigmoid_f(acc[0][r]);
                const float gf = sigmoid_f(acc[1][r]);
                const float gg = tanh_f(acc[2][r]);
                const float go = sigmoid_f(acc[3][r]);
                c0[r] = gf * c0[r] + gi * gg;
                const float hv = go * tanh_f(c0[r]);
                const unsigned short hb = f2b(hv);
                const int idx = q * HSZ + (quad * 4 + r) * PH + w * 16 + l16;
                h0h[idx] = hb; h0o[idx] = f2b(hv - b2f(hb));
            }
            __syncthreads();
            bf16x8 ah[2], ao[2], bh[2], bo[2];
            #pragma unroll
            for (int ks = 0; ks < 2; ++ks) {
                ah[ks] = *(const bf16x8*)&h0h[q * HSZ + l16 * PH + ks * 32 + k0];
                ao[ks] = *(const bf16x8*)&h0o[q * HSZ + l16 * PH + ks * 32 + k0];
                bh[ks] = *(const bf16x8*)&h1h[p * HSZ + l16 * PH + ks * 32 + k0];
                bo[ks] = *(const bf16x8*)&h1o[p * HSZ + l16 * PH + ks * 32 + k0];
            }
            #pragma unroll
            for (int g = 0; g < 4; ++g)
                acc[g] = (f32x4){gb1r[g], gb1r[g], gb1r[g], gb1r[g]};
            #pragma unroll
            for (int g = 0; g < 4; ++g)
                #pragma unroll
                for (int ks = 0; ks < 2; ++ks) {
                    acc[g] = MFMA(ah[ks], fih1h[g][ks], acc[g]);
                    acc[g] = MFMA(ao[ks], fih1h[g][ks], acc[g]);
                    acc[g] = MFMA(bh[ks], fhh1h[g][ks], acc[g]);
                    acc[g] = MFMA(bo[ks], fhh1h[g][ks], acc[g]);
                    acc[g] = MFMA(ah[ks], fih1l[g][ks], acc[g]);
                    acc[g] = MFMA(bh[ks], fhh1l[g][ks], acc[g]);
                }
            #pragma unroll
            for (int r = 0; r < 4; ++r) {
                const float gi = sigmoid_f(acc[0][r]);
                const float gf = sigmoid_f(acc[1][r]);
                const float gg = tanh_f(acc[2][r]);
                const float go = sigmoid_f(acc[3][r]);
                c1[r] = gf * c1[r] + gi * gg;
                const float hv = go * tanh_f(c1[r]);
                const unsigned short hb = f2b(hv);
                const int idx = q * HSZ + (quad * 4 + r) * PH + w * 16 + l16;
                h1h[idx] = hb; h1o[idx] = f2b(hv - b2f(hb));
            }
            __syncthreads();
        }
    }
    const int n = tid & 127;
    const int mb = (tid >> 7) * 8;
    float s[8] = {0.f, 0.f, 0.f, 0.f, 0.f, 0.f, 0.f, 0.f};
    for (int k = 0; k < 64; ++k) {
        const float wv = wfcp[n * 64 + k];
        #pragma unroll
        for (int m = 0; m < 8; ++m) {
            const int idx = (mb + m) * PH + k;
            s[m] += (b2f(h1h[idx]) + b2f(h1o[idx])) * wv;
        }
    }
    #pragma unroll
    for (int m = 0; m < 8; ++m)
        out[(size_t)(b0 + mb + m) * 128 + n] = s[m] + bfcp[n];
}

extern "C" void kernel_launch(void* const* d_in, const int* in_sizes, int n_in,
                              void* d_out, int out_size, void* d_ws, size_t ws_size,
                              hipStream_t stream) {
    const float* x     = (const float*)d_in[0];
    const float* wih0  = (const float*)d_in[1];
    const float* whh0  = (const float*)d_in[2];
    const float* bih0  = (const float*)d_in[3];
    const float* bhh0  = (const float*)d_in[4];
    const float* wih1  = (const float*)d_in[5];
    const float* whh1  = (const float*)d_in[6];
    const float* bih1  = (const float*)d_in[7];
    const float* bhh1  = (const float*)d_in[8];
    const float* wfc   = (const float*)d_in[9];
    const float* bfc   = (const float*)d_in[10];
    float* out = (float*)d_out;

    const size_t xp_bytes = (size_t)1024 * 256 * 256 * sizeof(_Float16); // 134 MB
    if (ws_size >= xp_bytes) {
        _Float16* xp = (_Float16*)d_ws;
        proj0_kernel<<<256, 256, 0, stream>>>(x, wih0, bih0, bhh0, xp);
        rec_kernel<<<64, 256, 0, stream>>>(xp, whh0, wih1, whh1, bih1, bhh1,
                                           wfc, bfc, out);
    } else {
        const size_t lds_bytes = (16 * XPI + 8 * HSZ) * sizeof(unsigned short);
        mega_fb<<<64, 256, lds_bytes, stream>>>(x, wih0, whh0, bih0, bhh0,
                                                wih1, whh1, bih1, bhh1, wfc, bfc, out);
    }
}